// Round 1
// baseline (2010.105 us; speedup 1.0000x reference)
//
#include <hip/hip_runtime.h>
#include <math.h>

// ---------------- problem constants ----------------
constexpr int BB = 32, PP = 49, EE = 256, VV = 32000, TT = 48, ST = 47;
#define AP 260   // As row stride (256 + 4 pad)
#define BP 68    // Bs row stride (64 + 4 pad)

// ---------------- ws layout (float offsets) ----------------
constexpr long long OFF_HBUF = 0;          // 2 * 32*256 ping-pong h
constexpr long long OFF_M0   = 16384;      // 32*256
constexpr long long OFF_GS   = 24576;      // 32*1024 g_static (+bih+bhh)
constexpr long long OFF_GPRE = 57344;      // 47*1024*32  [t][j4][b]
constexpr long long OFF_V    = 1597440;    // 32*49*256   [(b,p)][j]
constexpr long long OFF_HALL = 1998848;    // 1504*256    [(b,t)][j]
constexpr long long OFF_FO   = 2383872;    // 1504*512
constexpr long long OFF_HS   = 3153920;    // 1504*512  (_hh | _s)
constexpr long long OFF_CE   = 3923968;    // 1504*256  (c + hh)
constexpr long long OFF_PMAX = 4308992;    // 1504*500
constexpr long long OFF_PSUM = 5060992;    // 1504*500
constexpr long long OFF_PAI  = 5812992;    // 1504*500 (int)
constexpr long long OFF_ROWM = 6564992;    // 1504
constexpr long long OFF_ROWLS= 6566496;    // 1504
constexpr long long OFF_CNT  = 6568000;    // barrier counter (int)

// d_out layout: att [0,75200) ; logp [75200, 48203200) ; txt [48203200, 48204704)
constexpr long long OUT_LOGP = 75200;
constexpr long long OUT_TXT  = 48203200;

__device__ __forceinline__ float sigf(float x) { return 1.0f / (1.0f + expf(-x)); }

// ---------------- generic 47/49-row x 64-col fp32 GEMM tile, K=256 ----------------
// 256 threads: cg = tid&15 owns 4 cols, rg = tid>>4 owns RPT contiguous rows.
template <int RPT, typename ALoad, typename Epi>
__device__ __forceinline__ void gemm_tile(
    float* As, float* Bs, int r_count,
    const float* __restrict__ Bglob, int ldb, int koff, int n0,
    ALoad aload, Epi epi)
{
  const int tid = threadIdx.x;
  const int cg = tid & 15, rg = tid >> 4;
  const int rbase = rg * RPT;

  // stage A rows (k = tid, coalesced)
  for (int r = 0; r < r_count; ++r) As[r * AP + tid] = aload(r, tid);

  float acc[RPT][4];
#pragma unroll
  for (int j = 0; j < RPT; ++j)
#pragma unroll
    for (int c = 0; c < 4; ++c) acc[j][c] = 0.f;

  for (int kc0 = 0; kc0 < 256; kc0 += 32) {
    __syncthreads();
    { // stage B chunk transposed: Bs[kc][c]
      int c = tid >> 2, kq = (tid & 3) * 8;
      const float* src = Bglob + (long long)(n0 + c) * ldb + koff + kc0 + kq;
      float4 x0 = *(const float4*)src;
      float4 x1 = *(const float4*)(src + 4);
      Bs[(kq + 0) * BP + c] = x0.x; Bs[(kq + 1) * BP + c] = x0.y;
      Bs[(kq + 2) * BP + c] = x0.z; Bs[(kq + 3) * BP + c] = x0.w;
      Bs[(kq + 4) * BP + c] = x1.x; Bs[(kq + 5) * BP + c] = x1.y;
      Bs[(kq + 6) * BP + c] = x1.z; Bs[(kq + 7) * BP + c] = x1.w;
    }
    __syncthreads();
#pragma unroll
    for (int kc = 0; kc < 32; kc += 4) {
      float4 b0 = *(float4*)&Bs[(kc + 0) * BP + cg * 4];
      float4 b1 = *(float4*)&Bs[(kc + 1) * BP + cg * 4];
      float4 b2 = *(float4*)&Bs[(kc + 2) * BP + cg * 4];
      float4 b3 = *(float4*)&Bs[(kc + 3) * BP + cg * 4];
#pragma unroll
      for (int j = 0; j < RPT; ++j) {
        int r = rbase + j;
        if (r < r_count) {
          float4 a = *(float4*)&As[r * AP + kc0 + kc];
          acc[j][0] += a.x * b0.x + a.y * b1.x + a.z * b2.x + a.w * b3.x;
          acc[j][1] += a.x * b0.y + a.y * b1.y + a.z * b2.y + a.w * b3.y;
          acc[j][2] += a.x * b0.z + a.y * b1.z + a.z * b2.z + a.w * b3.z;
          acc[j][3] += a.x * b0.w + a.y * b1.w + a.z * b2.w + a.w * b3.w;
        }
      }
    }
  }
#pragma unroll
  for (int j = 0; j < RPT; ++j) {
    int r = rbase + j;
    if (r < r_count) {
      float4 o = make_float4(acc[j][0], acc[j][1], acc[j][2], acc[j][3]);
      epi(r, cg * 4, o);
    }
  }
}

// ---------------- k_prep: mean, h0, m0, g_static ----------------
__global__ __launch_bounds__(256) void k_prep(
    const float* __restrict__ image, const float* __restrict__ vp,
    const float* __restrict__ label, const float* __restrict__ topic,
    const float* __restrict__ Wh, const float* __restrict__ bh,
    const float* __restrict__ Wm, const float* __restrict__ bm,
    const float* __restrict__ Wih, const float* __restrict__ bih,
    const float* __restrict__ bhh, float* __restrict__ ws)
{
  __shared__ float xs[536];
  int b = blockIdx.x, tid = threadIdx.x;
  float s = 0.f;
  for (int p = 0; p < PP; ++p) s += image[(b * PP + p) * EE + tid];
  xs[tid] = s * (1.0f / 49.0f);
  if (tid < 8)  xs[256 + tid] = vp[b * 8 + tid];
  if (tid < 16) xs[264 + tid] = label[b * 16 + tid];
  xs[280 + tid] = topic[b * 256 + tid];
  __syncthreads();
  float ah = bh[tid], am = bm[tid];
  for (int k = 0; k < 256; ++k) {
    float mk = xs[k];
    ah += mk * Wh[tid * 256 + k];
    am += mk * Wm[tid * 256 + k];
  }
  ws[OFF_HBUF + b * 256 + tid] = tanhf(ah);
  ws[OFF_M0   + b * 256 + tid] = tanhf(am);
  float a0 = bih[tid]       + bhh[tid];
  float a1 = bih[256 + tid] + bhh[256 + tid];
  float a2 = bih[512 + tid] + bhh[512 + tid];
  float a3 = bih[768 + tid] + bhh[768 + tid];
  for (int k = 0; k < 536; ++k) {
    float xk = xs[k];
    a0 += xk * Wih[(0 * 256 + tid) * 792 + k];
    a1 += xk * Wih[(1 * 256 + tid) * 792 + k];
    a2 += xk * Wih[(2 * 256 + tid) * 792 + k];
    a3 += xk * Wih[(3 * 256 + tid) * 792 + k];
  }
  float* gs = ws + OFF_GS + b * 1024;
  gs[tid] = a0; gs[256 + tid] = a1; gs[512 + tid] = a2; gs[768 + tid] = a3;
}

// ---------------- k_v: v = image @ Wv.T + bv ----------------
__global__ __launch_bounds__(256) void k_v(const float* __restrict__ image,
    const float* __restrict__ Wv, const float* __restrict__ bv, float* __restrict__ ws)
{
  __shared__ float As[PP * AP]; __shared__ float Bs[32 * BP];
  int nt = blockIdx.x, b = blockIdx.y, n0 = nt * 64;
  float* v = ws + OFF_V;
  gemm_tile<4>(As, Bs, 49, Wv, 256, 0, n0,
    [&](int r, int k) { return image[(b * PP + r) * EE + k]; },
    [&](int r, int c0, float4 o) {
      float4 bb = *(const float4*)&bv[n0 + c0];
      o.x += bb.x; o.y += bb.y; o.z += bb.z; o.w += bb.w;
      *(float4*)&v[(b * PP + r) * EE + n0 + c0] = o;
    });
}

// ---------------- k_gpre: gpre[t][j][b] = g_static + emb_t @ Wih_emb.T ----------------
__global__ __launch_bounds__(256) void k_gpre(const float* __restrict__ emb,
    const int* __restrict__ text, const float* __restrict__ Wih, float* __restrict__ ws)
{
  __shared__ float As[PP * AP]; __shared__ float Bs[32 * BP];
  int nt = blockIdx.x, b = blockIdx.y, n0 = nt * 64;
  const float* gs = ws + OFF_GS + b * 1024;
  float* gpre = ws + OFF_GPRE;
  gemm_tile<3>(As, Bs, 47, Wih, 792, 536, n0,
    [&](int r, int k) { return emb[(long long)text[b * TT + r] * EE + k]; },
    [&](int r, int c0, float4 o) {
      float* dst = gpre + (long long)r * 32768 + (n0 + c0) * 32 + b;
      dst[0]  = o.x + gs[n0 + c0];
      dst[32] = o.y + gs[n0 + c0 + 1];
      dst[64] = o.z + gs[n0 + c0 + 2];
      dst[96] = o.w + gs[n0 + c0 + 3];
    });
}

// ---------------- k_recur: persistent LSTM recurrence, 64 blocks x 128 thr ----------------
__global__ __launch_bounds__(128) void k_recur(const float* __restrict__ Whh,
    float* __restrict__ ws)
{
  __shared__ float wL[4096];       // [j_l][gate][k]   16 KB
  __shared__ float hL[32 * 257];   // padded h         32.9 KB
  int tid = threadIdx.x, bk = blockIdx.x;
  int j_l = tid >> 5, b = tid & 31;
  int j = bk * 4 + j_l;
  for (int idx = tid; idx < 4096; idx += 128) {
    int jl = idx >> 10, g = (idx >> 8) & 3, k = idx & 255;
    wL[idx] = Whh[((g << 8) + bk * 4 + jl) * 256 + k];
  }
  float m = ws[OFF_M0 + b * 256 + j];
  float* hbuf = ws + OFF_HBUF;
  const float* gpre = ws + OFF_GPRE;
  float* h_all = ws + OFF_HALL;
  int* cnt = (int*)(ws + OFF_CNT);
  for (int t = 0; t < ST; ++t) {
    int par = t & 1;
    const float* hsrc = hbuf + par * 8192;
    for (int idx = tid; idx < 8192; idx += 128)
      hL[(idx >> 8) * 257 + (idx & 255)] = hsrc[idx];
    __syncthreads();
    const float* gp = gpre + (long long)t * 32768;
    float ai = gp[((0 << 8) + j) * 32 + b];
    float af = gp[((1 << 8) + j) * 32 + b];
    float ag = gp[((2 << 8) + j) * 32 + b];
    float ao = gp[((3 << 8) + j) * 32 + b];
    const float* wp = wL + j_l * 1024;
    const float* hp = hL + b * 257;
    for (int k = 0; k < 256; k += 4) {
      float4 wi = *(const float4*)&wp[k];
      float4 wf = *(const float4*)&wp[256 + k];
      float4 wg = *(const float4*)&wp[512 + k];
      float4 wo = *(const float4*)&wp[768 + k];
      float h0 = hp[k], h1 = hp[k + 1], h2 = hp[k + 2], h3 = hp[k + 3];
      ai += wi.x * h0 + wi.y * h1 + wi.z * h2 + wi.w * h3;
      af += wf.x * h0 + wf.y * h1 + wf.z * h2 + wf.w * h3;
      ag += wg.x * h0 + wg.y * h1 + wg.z * h2 + wg.w * h3;
      ao += wo.x * h0 + wo.y * h1 + wo.z * h2 + wo.w * h3;
    }
    m = sigf(af) * m + sigf(ai) * tanhf(ag);
    float h = sigf(ao) * tanhf(m);
    hbuf[(1 - par) * 8192 + b * 256 + j] = h;
    h_all[(long long)(b * ST + t) * 256 + j] = h;
    // grid barrier (monotonic count, 64 blocks, all co-resident)
    __threadfence();
    __syncthreads();
    if (tid == 0) {
      __hip_atomic_fetch_add(cnt, 1, __ATOMIC_RELEASE, __HIP_MEMORY_SCOPE_AGENT);
      while (__hip_atomic_load(cnt, __ATOMIC_ACQUIRE, __HIP_MEMORY_SCOPE_AGENT) < 64 * (t + 1)) {
        __builtin_amdgcn_s_sleep(1);
      }
      __threadfence();
    }
    __syncthreads();
  }
}

// ---------------- k_fc: FO = relu(h_all @ Wfc.T + bfc) ----------------
__global__ __launch_bounds__(256) void k_fc(const float* __restrict__ Wfc,
    const float* __restrict__ bfc, float* __restrict__ ws)
{
  __shared__ float As[PP * AP]; __shared__ float Bs[32 * BP];
  int nt = blockIdx.x, b = blockIdx.y, n0 = nt * 64;
  const float* h_all = ws + OFF_HALL;
  float* FO = ws + OFF_FO;
  gemm_tile<3>(As, Bs, 47, Wfc, 256, 0, n0,
    [&](int r, int k) { return h_all[(long long)(b * ST + r) * 256 + k]; },
    [&](int r, int c0, float4 o) {
      float4 bb = *(const float4*)&bfc[n0 + c0];
      o.x = fmaxf(o.x + bb.x, 0.f); o.y = fmaxf(o.y + bb.y, 0.f);
      o.z = fmaxf(o.z + bb.z, 0.f); o.w = fmaxf(o.w + bb.w, 0.f);
      *(float4*)&FO[(long long)(b * ST + r) * 512 + n0 + c0] = o;
    });
}

// ---------------- k_hs: _hh = hh@Whh2.T + bhh2 ; _s = s@Ws.T + bs ----------------
__global__ __launch_bounds__(256) void k_hs(const float* __restrict__ Whh2,
    const float* __restrict__ bhh2, const float* __restrict__ Wsw,
    const float* __restrict__ bsw, float* __restrict__ ws)
{
  __shared__ float As[PP * AP]; __shared__ float Bs[32 * BP];
  int nt = blockIdx.x, b = blockIdx.y;
  bool second = nt >= 4;
  int n0b = (nt & 3) * 64;
  const float* Bmat = second ? Wsw : Whh2;
  const float* bias = second ? bsw : bhh2;
  int aoff = second ? 256 : 0;
  int oout = second ? 256 : 0;
  const float* FO = ws + OFF_FO;
  float* HS = ws + OFF_HS;
  gemm_tile<3>(As, Bs, 47, Bmat, 256, 0, n0b,
    [&](int r, int k) { return FO[(long long)(b * ST + r) * 512 + aoff + k]; },
    [&](int r, int c0, float4 o) {
      float4 bb = *(const float4*)&bias[n0b + c0];
      o.x += bb.x; o.y += bb.y; o.z += bb.z; o.w += bb.w;
      *(float4*)&HS[(long long)(b * ST + r) * 512 + oout + n0b + c0] = o;
    });
}

// ---------------- k_att: z/zz/softmax/c/ce per valid (b,t) ----------------
__global__ __launch_bounds__(256) void k_att(const float* __restrict__ image,
    const float* __restrict__ Wz, const float* __restrict__ bz,
    const int* __restrict__ length, float* __restrict__ ws, float* __restrict__ out)
{
  int t = blockIdx.x, b = blockIdx.y, tid = threadIdx.x;
  int i = b * ST + t;
  float* att = out;
  bool valid = t < (length[b] - 1);
  if (!valid) {
    if (tid < 50) att[(long long)i * 50 + tid] = 0.f;
    return;
  }
  __shared__ float hhL[256], sL[256], hbL[256], sbL[256];
  __shared__ float zzL[52], aL[52];
  const float* FO = ws + OFF_FO;
  const float* HS = ws + OFF_HS;
  const float* v  = ws + OFF_V;
  float* CE = ws + OFF_CE;
  hhL[tid] = FO[(long long)i * 512 + tid];
  sL[tid]  = FO[(long long)i * 512 + 256 + tid];
  hbL[tid] = HS[(long long)i * 512 + tid];
  sbL[tid] = HS[(long long)i * 512 + 256 + tid];
  __syncthreads();
  int w = tid >> 6, l = tid & 63;
  for (int p = w; p < 50; p += 4) {
    int j0 = l * 4;
    float x0, x1, x2, x3;
    if (p < 49) {
      float4 vv = *(const float4*)&v[(long long)(b * PP + p) * EE + j0];
      x0 = vv.x; x1 = vv.y; x2 = vv.z; x3 = vv.w;
    } else {
      x0 = sbL[j0]; x1 = sbL[j0 + 1]; x2 = sbL[j0 + 2]; x3 = sbL[j0 + 3];
    }
    float4 wz4 = *(const float4*)&Wz[j0];
    float part = tanhf(x0 + hbL[j0]) * wz4.x + tanhf(x1 + hbL[j0 + 1]) * wz4.y
               + tanhf(x2 + hbL[j0 + 2]) * wz4.z + tanhf(x3 + hbL[j0 + 3]) * wz4.w;
    for (int o = 32; o; o >>= 1) part += __shfl_down(part, o, 64);
    if (l == 0) zzL[p] = part + bz[0];
  }
  __syncthreads();
  if (tid < 64) {
    float zv = (tid < 50) ? zzL[tid] : -3.4e38f;
    float mx = zv;
    for (int o = 32; o; o >>= 1) mx = fmaxf(mx, __shfl_xor(mx, o, 64));
    float e = (tid < 50) ? expf(zv - mx) : 0.f;
    float ssum = e;
    for (int o = 32; o; o >>= 1) ssum += __shfl_xor(ssum, o, 64);
    if (tid < 50) {
      float a = e / ssum;
      aL[tid] = a;
      att[(long long)i * 50 + tid] = a;
    }
  }
  __syncthreads();
  float cj = 0.f;
  for (int p = 0; p < 49; ++p) cj += aL[p] * image[(long long)(b * PP + p) * EE + tid];
  cj += aL[49] * sL[tid];
  CE[(long long)i * 256 + tid] = cj + hhL[tid];
}

// ---------------- k_D: logits GEMM + per-tile softmax/argmax partials ----------------
__global__ __launch_bounds__(256) void k_D(const float* __restrict__ Wp,
    const float* __restrict__ bp, const int* __restrict__ length,
    const float* __restrict__ temp, float* __restrict__ ws, float* __restrict__ out)
{
  __shared__ float As[PP * AP]; __shared__ float Bs[32 * BP];
  int nt = blockIdx.x, b = blockIdx.y, n0 = nt * 64, tid = threadIdx.x;
  int cg = tid & 15, rg = tid >> 4, rbase = rg * 3;
  int Lb = length[b] - 1; if (Lb > ST) Lb = ST;
  const float* CE = ws + OFF_CE;
  float* logp = out + OUT_LOGP;
  float4 sav[3];
  gemm_tile<3>(As, Bs, Lb, Wp, 256, 0, n0,
    [&](int r, int k) { return CE[(long long)(b * ST + r) * 256 + k]; },
    [&](int r, int c0, float4 o) {
      float4 bb = *(const float4*)&bp[n0 + c0];
      o.x += bb.x; o.y += bb.y; o.z += bb.z; o.w += bb.w;
      *(float4*)&logp[(long long)(b * ST + r) * VV + n0 + c0] = o;
      sav[r - rbase] = o;
    });
  __syncthreads();
  // reuse As as reduction scratch
  float* redS = As;              // [48][16]
  float* redV = As + 768;        // [48][16]
  int*   redI = (int*)(As + 1536);
  float* rowm = As + 2304;       // [48]
  float it = 1.0f / temp[b];
#pragma unroll
  for (int jj = 0; jj < 3; ++jj) {
    int r = rbase + jj;
    if (r < Lb) {
      float4 o = sav[jj];
      redV[r * 16 + cg] = fmaxf(fmaxf(o.x, o.y), fmaxf(o.z, o.w));
    }
  }
  __syncthreads();
  if (cg == 0) {
#pragma unroll
    for (int jj = 0; jj < 3; ++jj) {
      int r = rbase + jj;
      if (r < Lb) {
        float mm = redV[r * 16];
        for (int u = 1; u < 16; ++u) mm = fmaxf(mm, redV[r * 16 + u]);
        rowm[r] = mm;
      }
    }
  }
  __syncthreads();
#pragma unroll
  for (int jj = 0; jj < 3; ++jj) {
    int r = rbase + jj;
    if (r < Lb) {
      float rm = rowm[r];
      float4 o = sav[jj];
      redS[r * 16 + cg] = expf((o.x - rm) * it) + expf((o.y - rm) * it)
                        + expf((o.z - rm) * it) + expf((o.w - rm) * it);
      float bvv = o.x; int bii = 0;
      if (o.y > bvv) { bvv = o.y; bii = 1; }
      if (o.z > bvv) { bvv = o.z; bii = 2; }
      if (o.w > bvv) { bvv = o.w; bii = 3; }
      redI[r * 16 + cg] = n0 + cg * 4 + bii;
    }
  }
  __syncthreads();
  if (cg == 0) {
    float* pmax = ws + OFF_PMAX; float* psum = ws + OFF_PSUM;
    int* pai = (int*)(ws + OFF_PAI);
#pragma unroll
    for (int jj = 0; jj < 3; ++jj) {
      int r = rbase + jj;
      if (r < Lb) {
        float S = 0.f; float bvv = -3.4e38f; int bii = 0;
        for (int u = 0; u < 16; ++u) {
          S += redS[r * 16 + u];
          float vv = redV[r * 16 + u];
          if (vv > bvv) { bvv = vv; bii = redI[r * 16 + u]; }
        }
        long long ii = (long long)(b * ST + r) * 500 + nt;
        pmax[ii] = rowm[r];
        psum[ii] = S;
        pai[ii]  = bii;
      }
    }
  }
}

// ---------------- k_E0: reduce per-tile partials -> row stats + txt ----------------
__global__ __launch_bounds__(256) void k_E0(const int* __restrict__ length,
    const float* __restrict__ temp, float* __restrict__ ws, float* __restrict__ out)
{
  int i = blockIdx.x, tid = threadIdx.x;
  int b = i / ST, t = i % ST;
  float* txt = out + OUT_TXT;
  if (t >= length[b] - 1) { if (tid == 0) txt[i] = 0.f; return; }
  const float* pmax = ws + OFF_PMAX + (long long)i * 500;
  const float* psum = ws + OFF_PSUM + (long long)i * 500;
  const int* pai = (int*)(ws + OFF_PAI) + (long long)i * 500;
  __shared__ float sred[4]; __shared__ float s2[4]; __shared__ float s3[4]; __shared__ int s4[4];
  int w = tid >> 6;
  float mx = -3.4e38f;
  for (int nt = tid; nt < 500; nt += 256) mx = fmaxf(mx, pmax[nt]);
  for (int o = 32; o; o >>= 1) mx = fmaxf(mx, __shfl_xor(mx, o, 64));
  if ((tid & 63) == 0) sred[w] = mx;
  __syncthreads();
  float M = fmaxf(fmaxf(sred[0], sred[1]), fmaxf(sred[2], sred[3]));
  float it = 1.0f / temp[b];
  float S = 0.f; float bv = -3.4e38f; int bi = 0;
  for (int nt = tid; nt < 500; nt += 256) {
    float pm = pmax[nt];
    S += psum[nt] * expf((pm - M) * it);
    int ii = pai[nt];
    if (pm > bv || (pm == bv && ii < bi)) { bv = pm; bi = ii; }
  }
  for (int o = 32; o; o >>= 1) {
    S += __shfl_xor(S, o, 64);
    float vv = __shfl_xor(bv, o, 64);
    int ii = __shfl_xor(bi, o, 64);
    if (vv > bv || (vv == bv && ii < bi)) { bv = vv; bi = ii; }
  }
  if ((tid & 63) == 0) { s2[w] = S; s3[w] = bv; s4[w] = bi; }
  __syncthreads();
  if (tid == 0) {
    float St = s2[0] + s2[1] + s2[2] + s2[3];
    float bvv = s3[0]; int bii = s4[0];
    for (int u = 1; u < 4; ++u)
      if (s3[u] > bvv || (s3[u] == bvv && s4[u] < bii)) { bvv = s3[u]; bii = s4[u]; }
    ws[OFF_ROWM + i] = M;
    ws[OFF_ROWLS + i] = logf(St);
    txt[i] = (float)bii;
  }
}

// ---------------- k_E: in-place logits -> logp (or 0 for invalid rows) ----------------
__global__ __launch_bounds__(256) void k_E(const int* __restrict__ length,
    const float* __restrict__ temp, const float* __restrict__ ws, float* __restrict__ out)
{
  int i = blockIdx.y;
  int f4 = blockIdx.x * 256 + threadIdx.x;
  if (f4 >= 8000) return;
  int b = i / ST, t = i % ST;
  float4* p = (float4*)(out + OUT_LOGP + (long long)i * VV) + f4;
  if (t >= length[b] - 1) { *p = make_float4(0.f, 0.f, 0.f, 0.f); return; }
  float M = ws[OFF_ROWM + i], LS = ws[OFF_ROWLS + i];
  float it = 1.0f / temp[b];
  float4 x = *p;
  x.x = (x.x - M) * it - LS;
  x.y = (x.y - M) * it - LS;
  x.z = (x.z - M) * it - LS;
  x.w = (x.w - M) * it - LS;
  *p = x;
}

// ---------------- launch ----------------
extern "C" void kernel_launch(void* const* d_in, const int* in_sizes, int n_in,
                              void* d_out, int out_size, void* d_ws, size_t ws_size,
                              hipStream_t stream) {
  const float* image = (const float*)d_in[0];
  const float* vp    = (const float*)d_in[1];
  const float* label = (const float*)d_in[2];
  const float* topic = (const float*)d_in[3];
  const float* temp  = (const float*)d_in[4];
  const int*   text  = (const int*)d_in[5];
  const int*   length= (const int*)d_in[6];
  const float* emb   = (const float*)d_in[7];
  const float* Wv  = (const float*)d_in[8];  const float* bv  = (const float*)d_in[9];
  const float* Wh  = (const float*)d_in[10]; const float* bh  = (const float*)d_in[11];
  const float* Wm  = (const float*)d_in[12]; const float* bm  = (const float*)d_in[13];
  const float* Wih = (const float*)d_in[14]; const float* bih = (const float*)d_in[15];
  const float* Whh = (const float*)d_in[16]; const float* bhh = (const float*)d_in[17];
  const float* Wfc = (const float*)d_in[18]; const float* bfc = (const float*)d_in[19];
  const float* Whh2= (const float*)d_in[20]; const float* bhh2= (const float*)d_in[21];
  const float* Wsw = (const float*)d_in[22]; const float* bsw = (const float*)d_in[23];
  const float* Wz  = (const float*)d_in[24]; const float* bz  = (const float*)d_in[25];
  const float* Wp  = (const float*)d_in[26]; const float* bp  = (const float*)d_in[27];
  float* ws = (float*)d_ws;
  float* out = (float*)d_out;

  hipMemsetAsync(ws + OFF_CNT, 0, 64, stream);
  k_prep<<<32, 256, 0, stream>>>(image, vp, label, topic, Wh, bh, Wm, bm, Wih, bih, bhh, ws);
  k_v<<<dim3(4, 32), 256, 0, stream>>>(image, Wv, bv, ws);
  k_gpre<<<dim3(16, 32), 256, 0, stream>>>(emb, text, Wih, ws);
  k_recur<<<64, 128, 0, stream>>>(Whh, ws);
  k_fc<<<dim3(8, 32), 256, 0, stream>>>(Wfc, bfc, ws);
  k_hs<<<dim3(8, 32), 256, 0, stream>>>(Whh2, bhh2, Wsw, bsw, ws);
  k_att<<<dim3(47, 32), 256, 0, stream>>>(image, Wz, bz, length, ws, out);
  k_D<<<dim3(500, 32), 256, 0, stream>>>(Wp, bp, length, temp, ws, out);
  k_E0<<<1504, 256, 0, stream>>>(length, temp, ws, out);
  k_E<<<dim3(32, 1504), 256, 0, stream>>>(length, temp, ws, out);
}

// Round 2
// 1406.928 us; speedup vs baseline: 1.4287x; 1.4287x over previous
//
#include <hip/hip_runtime.h>
#include <math.h>

// ---------------- problem constants ----------------
constexpr int BB = 32, PP = 49, EE = 256, VV = 32000, TT = 48, ST = 47;
#define AP 260   // As row stride (256 + 4 pad)
#define BP 68    // Bs row stride (64 + 4 pad)

// ---------------- ws layout (float offsets) ----------------
constexpr long long OFF_HBUF = 0;          // 2 * 32*256 ping-pong h
constexpr long long OFF_M0   = 16384;      // 32*256
constexpr long long OFF_GS   = 24576;      // 32*1024 g_static (+bih+bhh)
constexpr long long OFF_GPRE = 57344;      // 47*1024*32  [t][j4][b]
constexpr long long OFF_V    = 1597440;    // 32*49*256   [(b,p)][j]
constexpr long long OFF_HALL = 1998848;    // 1504*256    [(b,t)][j]
constexpr long long OFF_FO   = 2383872;    // 1504*512
constexpr long long OFF_HS   = 3153920;    // 1504*512  (_hh | _s)
constexpr long long OFF_CE   = 3923968;    // 1504*256  (c + hh)
constexpr long long OFF_PMAX = 4308992;    // 1504*500
constexpr long long OFF_PSUM = 5060992;    // 1504*500
constexpr long long OFF_PAI  = 5812992;    // 1504*500 (int)
constexpr long long OFF_ROWM = 6564992;    // 1504
constexpr long long OFF_ROWLS= 6566496;    // 1504
constexpr long long OFF_CNT  = 6568000;    // barrier counter (int)
// B_hi recycled over GPRE..CE (dead after k_att): 8.192M bf16 = 4.096M floats
constexpr long long OFF_BHI  = 57344;      // ends 4251648 < OFF_PMAX  (bf16)
constexpr long long OFF_AHI  = 6568064;    // 1536*256 bf16 = 196608 floats
constexpr long long OFF_ALO  = 6764672;    // 196608 floats
constexpr long long OFF_BLO  = 6961280;    // 4.096M floats (bf16), ends 11155584

// d_out layout: att [0,75200) ; logp [75200, 48203200) ; txt [48203200, 48204704)
constexpr long long OUT_LOGP = 75200;
constexpr long long OUT_TXT  = 48203200;

typedef __attribute__((ext_vector_type(8))) short bf8v;   // 8 bf16
typedef __attribute__((ext_vector_type(4))) float f4v;    // 4 fp32

__device__ __forceinline__ float sigf(float x) { return 1.0f / (1.0f + expf(-x)); }

__device__ __forceinline__ unsigned short f2bf(float x) {
  unsigned u = __float_as_uint(x);
  u += 0x7fffu + ((u >> 16) & 1u);   // round-to-nearest-even
  return (unsigned short)(u >> 16);
}

// ---------------- generic 47/49-row x 64-col fp32 GEMM tile, K=256 ----------------
template <int RPT, typename ALoad, typename Epi>
__device__ __forceinline__ void gemm_tile(
    float* As, float* Bs, int r_count,
    const float* __restrict__ Bglob, int ldb, int koff, int n0,
    ALoad aload, Epi epi)
{
  const int tid = threadIdx.x;
  const int cg = tid & 15, rg = tid >> 4;
  const int rbase = rg * RPT;

  for (int r = 0; r < r_count; ++r) As[r * AP + tid] = aload(r, tid);

  float acc[RPT][4];
#pragma unroll
  for (int j = 0; j < RPT; ++j)
#pragma unroll
    for (int c = 0; c < 4; ++c) acc[j][c] = 0.f;

  for (int kc0 = 0; kc0 < 256; kc0 += 32) {
    __syncthreads();
    {
      int c = tid >> 2, kq = (tid & 3) * 8;
      const float* src = Bglob + (long long)(n0 + c) * ldb + koff + kc0 + kq;
      float4 x0 = *(const float4*)src;
      float4 x1 = *(const float4*)(src + 4);
      Bs[(kq + 0) * BP + c] = x0.x; Bs[(kq + 1) * BP + c] = x0.y;
      Bs[(kq + 2) * BP + c] = x0.z; Bs[(kq + 3) * BP + c] = x0.w;
      Bs[(kq + 4) * BP + c] = x1.x; Bs[(kq + 5) * BP + c] = x1.y;
      Bs[(kq + 6) * BP + c] = x1.z; Bs[(kq + 7) * BP + c] = x1.w;
    }
    __syncthreads();
#pragma unroll
    for (int kc = 0; kc < 32; kc += 4) {
      float4 b0 = *(float4*)&Bs[(kc + 0) * BP + cg * 4];
      float4 b1 = *(float4*)&Bs[(kc + 1) * BP + cg * 4];
      float4 b2 = *(float4*)&Bs[(kc + 2) * BP + cg * 4];
      float4 b3 = *(float4*)&Bs[(kc + 3) * BP + cg * 4];
#pragma unroll
      for (int j = 0; j < RPT; ++j) {
        int r = rbase + j;
        if (r < r_count) {
          float4 a = *(float4*)&As[r * AP + kc0 + kc];
          acc[j][0] += a.x * b0.x + a.y * b1.x + a.z * b2.x + a.w * b3.x;
          acc[j][1] += a.x * b0.y + a.y * b1.y + a.z * b2.y + a.w * b3.y;
          acc[j][2] += a.x * b0.z + a.y * b1.z + a.z * b2.z + a.w * b3.z;
          acc[j][3] += a.x * b0.w + a.y * b1.w + a.z * b2.w + a.w * b3.w;
        }
      }
    }
  }
#pragma unroll
  for (int j = 0; j < RPT; ++j) {
    int r = rbase + j;
    if (r < r_count) {
      float4 o = make_float4(acc[j][0], acc[j][1], acc[j][2], acc[j][3]);
      epi(r, cg * 4, o);
    }
  }
}

// ---------------- k_prep: mean, h0, m0, g_static ----------------
__global__ __launch_bounds__(256) void k_prep(
    const float* __restrict__ image, const float* __restrict__ vp,
    const float* __restrict__ label, const float* __restrict__ topic,
    const float* __restrict__ Wh, const float* __restrict__ bh,
    const float* __restrict__ Wm, const float* __restrict__ bm,
    const float* __restrict__ Wih, const float* __restrict__ bih,
    const float* __restrict__ bhh, float* __restrict__ ws)
{
  __shared__ float xs[536];
  int b = blockIdx.x, tid = threadIdx.x;
  float s = 0.f;
  for (int p = 0; p < PP; ++p) s += image[(b * PP + p) * EE + tid];
  xs[tid] = s * (1.0f / 49.0f);
  if (tid < 8)  xs[256 + tid] = vp[b * 8 + tid];
  if (tid < 16) xs[264 + tid] = label[b * 16 + tid];
  xs[280 + tid] = topic[b * 256 + tid];
  __syncthreads();
  float ah = bh[tid], am = bm[tid];
  for (int k = 0; k < 256; ++k) {
    float mk = xs[k];
    ah += mk * Wh[tid * 256 + k];
    am += mk * Wm[tid * 256 + k];
  }
  ws[OFF_HBUF + b * 256 + tid] = tanhf(ah);
  ws[OFF_M0   + b * 256 + tid] = tanhf(am);
  float a0 = bih[tid]       + bhh[tid];
  float a1 = bih[256 + tid] + bhh[256 + tid];
  float a2 = bih[512 + tid] + bhh[512 + tid];
  float a3 = bih[768 + tid] + bhh[768 + tid];
  for (int k = 0; k < 536; ++k) {
    float xk = xs[k];
    a0 += xk * Wih[(0 * 256 + tid) * 792 + k];
    a1 += xk * Wih[(1 * 256 + tid) * 792 + k];
    a2 += xk * Wih[(2 * 256 + tid) * 792 + k];
    a3 += xk * Wih[(3 * 256 + tid) * 792 + k];
  }
  float* gs = ws + OFF_GS + b * 1024;
  gs[tid] = a0; gs[256 + tid] = a1; gs[512 + tid] = a2; gs[768 + tid] = a3;
}

// ---------------- k_v: v = image @ Wv.T + bv ----------------
__global__ __launch_bounds__(256) void k_v(const float* __restrict__ image,
    const float* __restrict__ Wv, const float* __restrict__ bv, float* __restrict__ ws)
{
  __shared__ float As[PP * AP]; __shared__ float Bs[32 * BP];
  int nt = blockIdx.x, b = blockIdx.y, n0 = nt * 64;
  float* v = ws + OFF_V;
  gemm_tile<4>(As, Bs, 49, Wv, 256, 0, n0,
    [&](int r, int k) { return image[(b * PP + r) * EE + k]; },
    [&](int r, int c0, float4 o) {
      float4 bb = *(const float4*)&bv[n0 + c0];
      o.x += bb.x; o.y += bb.y; o.z += bb.z; o.w += bb.w;
      *(float4*)&v[(b * PP + r) * EE + n0 + c0] = o;
    });
}

// ---------------- k_gpre ----------------
__global__ __launch_bounds__(256) void k_gpre(const float* __restrict__ emb,
    const int* __restrict__ text, const float* __restrict__ Wih, float* __restrict__ ws)
{
  __shared__ float As[PP * AP]; __shared__ float Bs[32 * BP];
  int nt = blockIdx.x, b = blockIdx.y, n0 = nt * 64;
  const float* gs = ws + OFF_GS + b * 1024;
  float* gpre = ws + OFF_GPRE;
  gemm_tile<3>(As, Bs, 47, Wih, 792, 536, n0,
    [&](int r, int k) { return emb[(long long)text[b * TT + r] * EE + k]; },
    [&](int r, int c0, float4 o) {
      float* dst = gpre + (long long)r * 32768 + (n0 + c0) * 32 + b;
      dst[0]  = o.x + gs[n0 + c0];
      dst[32] = o.y + gs[n0 + c0 + 1];
      dst[64] = o.z + gs[n0 + c0 + 2];
      dst[96] = o.w + gs[n0 + c0 + 3];
    });
}

// ---------------- k_recur: persistent LSTM recurrence ----------------
__global__ __launch_bounds__(128) void k_recur(const float* __restrict__ Whh,
    float* __restrict__ ws)
{
  __shared__ float wL[4096];
  __shared__ float hL[32 * 257];
  int tid = threadIdx.x, bk = blockIdx.x;
  int j_l = tid >> 5, b = tid & 31;
  int j = bk * 4 + j_l;
  for (int idx = tid; idx < 4096; idx += 128) {
    int jl = idx >> 10, g = (idx >> 8) & 3, k = idx & 255;
    wL[idx] = Whh[((g << 8) + bk * 4 + jl) * 256 + k];
  }
  float m = ws[OFF_M0 + b * 256 + j];
  float* hbuf = ws + OFF_HBUF;
  const float* gpre = ws + OFF_GPRE;
  float* h_all = ws + OFF_HALL;
  int* cnt = (int*)(ws + OFF_CNT);
  for (int t = 0; t < ST; ++t) {
    int par = t & 1;
    const float* hsrc = hbuf + par * 8192;
    for (int idx = tid; idx < 8192; idx += 128)
      hL[(idx >> 8) * 257 + (idx & 255)] = hsrc[idx];
    __syncthreads();
    const float* gp = gpre + (long long)t * 32768;
    float ai = gp[((0 << 8) + j) * 32 + b];
    float af = gp[((1 << 8) + j) * 32 + b];
    float ag = gp[((2 << 8) + j) * 32 + b];
    float ao = gp[((3 << 8) + j) * 32 + b];
    const float* wp = wL + j_l * 1024;
    const float* hp = hL + b * 257;
    for (int k = 0; k < 256; k += 4) {
      float4 wi = *(const float4*)&wp[k];
      float4 wf = *(const float4*)&wp[256 + k];
      float4 wg = *(const float4*)&wp[512 + k];
      float4 wo = *(const float4*)&wp[768 + k];
      float h0 = hp[k], h1 = hp[k + 1], h2 = hp[k + 2], h3 = hp[k + 3];
      ai += wi.x * h0 + wi.y * h1 + wi.z * h2 + wi.w * h3;
      af += wf.x * h0 + wf.y * h1 + wf.z * h2 + wf.w * h3;
      ag += wg.x * h0 + wg.y * h1 + wg.z * h2 + wg.w * h3;
      ao += wo.x * h0 + wo.y * h1 + wo.z * h2 + wo.w * h3;
    }
    m = sigf(af) * m + sigf(ai) * tanhf(ag);
    float h = sigf(ao) * tanhf(m);
    hbuf[(1 - par) * 8192 + b * 256 + j] = h;
    h_all[(long long)(b * ST + t) * 256 + j] = h;
    __threadfence();
    __syncthreads();
    if (tid == 0) {
      __hip_atomic_fetch_add(cnt, 1, __ATOMIC_RELEASE, __HIP_MEMORY_SCOPE_AGENT);
      while (__hip_atomic_load(cnt, __ATOMIC_ACQUIRE, __HIP_MEMORY_SCOPE_AGENT) < 64 * (t + 1)) {
        __builtin_amdgcn_s_sleep(1);
      }
      __threadfence();
    }
    __syncthreads();
  }
}

// ---------------- k_fc ----------------
__global__ __launch_bounds__(256) void k_fc(const float* __restrict__ Wfc,
    const float* __restrict__ bfc, float* __restrict__ ws)
{
  __shared__ float As[PP * AP]; __shared__ float Bs[32 * BP];
  int nt = blockIdx.x, b = blockIdx.y, n0 = nt * 64;
  const float* h_all = ws + OFF_HALL;
  float* FO = ws + OFF_FO;
  gemm_tile<3>(As, Bs, 47, Wfc, 256, 0, n0,
    [&](int r, int k) { return h_all[(long long)(b * ST + r) * 256 + k]; },
    [&](int r, int c0, float4 o) {
      float4 bb = *(const float4*)&bfc[n0 + c0];
      o.x = fmaxf(o.x + bb.x, 0.f); o.y = fmaxf(o.y + bb.y, 0.f);
      o.z = fmaxf(o.z + bb.z, 0.f); o.w = fmaxf(o.w + bb.w, 0.f);
      *(float4*)&FO[(long long)(b * ST + r) * 512 + n0 + c0] = o;
    });
}

// ---------------- k_hs ----------------
__global__ __launch_bounds__(256) void k_hs(const float* __restrict__ Whh2,
    const float* __restrict__ bhh2, const float* __restrict__ Wsw,
    const float* __restrict__ bsw, float* __restrict__ ws)
{
  __shared__ float As[PP * AP]; __shared__ float Bs[32 * BP];
  int nt = blockIdx.x, b = blockIdx.y;
  bool second = nt >= 4;
  int n0b = (nt & 3) * 64;
  const float* Bmat = second ? Wsw : Whh2;
  const float* bias = second ? bsw : bhh2;
  int aoff = second ? 256 : 0;
  int oout = second ? 256 : 0;
  const float* FO = ws + OFF_FO;
  float* HS = ws + OFF_HS;
  gemm_tile<3>(As, Bs, 47, Bmat, 256, 0, n0b,
    [&](int r, int k) { return FO[(long long)(b * ST + r) * 512 + aoff + k]; },
    [&](int r, int c0, float4 o) {
      float4 bb = *(const float4*)&bias[n0b + c0];
      o.x += bb.x; o.y += bb.y; o.z += bb.z; o.w += bb.w;
      *(float4*)&HS[(long long)(b * ST + r) * 512 + oout + n0b + c0] = o;
    });
}

// ---------------- k_att ----------------
__global__ __launch_bounds__(256) void k_att(const float* __restrict__ image,
    const float* __restrict__ Wz, const float* __restrict__ bz,
    const int* __restrict__ length, float* __restrict__ ws, float* __restrict__ out)
{
  int t = blockIdx.x, b = blockIdx.y, tid = threadIdx.x;
  int i = b * ST + t;
  float* att = out;
  bool valid = t < (length[b] - 1);
  if (!valid) {
    if (tid < 50) att[(long long)i * 50 + tid] = 0.f;
    return;
  }
  __shared__ float hhL[256], sL[256], hbL[256], sbL[256];
  __shared__ float zzL[52], aL[52];
  const float* FO = ws + OFF_FO;
  const float* HS = ws + OFF_HS;
  const float* v  = ws + OFF_V;
  float* CE = ws + OFF_CE;
  hhL[tid] = FO[(long long)i * 512 + tid];
  sL[tid]  = FO[(long long)i * 512 + 256 + tid];
  hbL[tid] = HS[(long long)i * 512 + tid];
  sbL[tid] = HS[(long long)i * 512 + 256 + tid];
  __syncthreads();
  int w = tid >> 6, l = tid & 63;
  for (int p = w; p < 50; p += 4) {
    int j0 = l * 4;
    float x0, x1, x2, x3;
    if (p < 49) {
      float4 vv = *(const float4*)&v[(long long)(b * PP + p) * EE + j0];
      x0 = vv.x; x1 = vv.y; x2 = vv.z; x3 = vv.w;
    } else {
      x0 = sbL[j0]; x1 = sbL[j0 + 1]; x2 = sbL[j0 + 2]; x3 = sbL[j0 + 3];
    }
    float4 wz4 = *(const float4*)&Wz[j0];
    float part = tanhf(x0 + hbL[j0]) * wz4.x + tanhf(x1 + hbL[j0 + 1]) * wz4.y
               + tanhf(x2 + hbL[j0 + 2]) * wz4.z + tanhf(x3 + hbL[j0 + 3]) * wz4.w;
    for (int o = 32; o; o >>= 1) part += __shfl_down(part, o, 64);
    if (l == 0) zzL[p] = part + bz[0];
  }
  __syncthreads();
  if (tid < 64) {
    float zv = (tid < 50) ? zzL[tid] : -3.4e38f;
    float mx = zv;
    for (int o = 32; o; o >>= 1) mx = fmaxf(mx, __shfl_xor(mx, o, 64));
    float e = (tid < 50) ? expf(zv - mx) : 0.f;
    float ssum = e;
    for (int o = 32; o; o >>= 1) ssum += __shfl_xor(ssum, o, 64);
    if (tid < 50) {
      float a = e / ssum;
      aL[tid] = a;
      att[(long long)i * 50 + tid] = a;
    }
  }
  __syncthreads();
  float cj = 0.f;
  for (int p = 0; p < 49; ++p) cj += aL[p] * image[(long long)(b * PP + p) * EE + tid];
  cj += aL[49] * sL[tid];
  CE[(long long)i * 256 + tid] = cj + hhL[tid];
}

// ---------------- k_cvtA: CE -> A-frag-layout bf16 hi/lo ----------------
// layout: [mt16][kc][lane][8], m = mt16*16 + (lane&15), k = kc*32 + (lane>>4)*8 + j
__global__ __launch_bounds__(256) void k_cvtA(float* __restrict__ ws)
{
  int gid = blockIdx.x * 256 + threadIdx.x;   // 0..49151 (96*8*64)
  int lane = gid & 63;
  int kc = (gid >> 6) & 7;
  int mt16 = gid >> 9;
  int m = (mt16 << 4) + (lane & 15);
  int k0 = (kc << 5) + ((lane >> 4) << 3);
  float xs[8];
  if (m < 1504) {
    const float* src = ws + OFF_CE + (long long)m * 256 + k0;
    float4 a = *(const float4*)src;
    float4 c = *(const float4*)(src + 4);
    xs[0] = a.x; xs[1] = a.y; xs[2] = a.z; xs[3] = a.w;
    xs[4] = c.x; xs[5] = c.y; xs[6] = c.z; xs[7] = c.w;
  } else {
#pragma unroll
    for (int j = 0; j < 8; ++j) xs[j] = 0.f;
  }
  bf8v vh, vl;
#pragma unroll
  for (int j = 0; j < 8; ++j) {
    unsigned short h = f2bf(xs[j]);
    vh[j] = (short)h;
    vl[j] = (short)f2bf(xs[j] - __uint_as_float((unsigned)h << 16));
  }
  ((bf8v*)(ws + OFF_AHI))[gid] = vh;
  ((bf8v*)(ws + OFF_ALO))[gid] = vl;
}

// ---------------- k_cvtB: Wp -> B-frag-layout bf16 hi/lo ----------------
// layout: [nt16][kc][lane][8], n = nt16*16 + (lane&15), k = kc*32 + (lane>>4)*8 + j
__global__ __launch_bounds__(256) void k_cvtB(const float* __restrict__ Wp,
                                              float* __restrict__ ws)
{
  int gid = blockIdx.x * 256 + threadIdx.x;   // 0..1023999 (2000*8*64)
  int lane = gid & 63;
  int kc = (gid >> 6) & 7;
  int nt16 = gid >> 9;
  int n = (nt16 << 4) + (lane & 15);
  int k0 = (kc << 5) + ((lane >> 4) << 3);
  const float* src = Wp + (long long)n * 256 + k0;
  float4 a = *(const float4*)src;
  float4 c = *(const float4*)(src + 4);
  float xs[8] = {a.x, a.y, a.z, a.w, c.x, c.y, c.z, c.w};
  bf8v vh, vl;
#pragma unroll
  for (int j = 0; j < 8; ++j) {
    unsigned short h = f2bf(xs[j]);
    vh[j] = (short)h;
    vl[j] = (short)f2bf(xs[j] - __uint_as_float((unsigned)h << 16));
  }
  ((bf8v*)(ws + OFF_BHI))[gid] = vh;
  ((bf8v*)(ws + OFF_BLO))[gid] = vl;
}

// ---------------- k_Dm: split-bf16 MFMA logits GEMM + softmax/argmax partials ----
// grid (24, 125): block tile M=64 x N=256, 4 waves (wave n-slice 64)
__global__ __launch_bounds__(256) void k_Dm(const float* __restrict__ bp,
    const float* __restrict__ temp, float* __restrict__ ws, float* __restrict__ out)
{
  int tid = threadIdx.x;
  int wv = tid >> 6, lane = tid & 63, ln = lane & 15, quad = lane >> 4;
  int m0 = blockIdx.x * 64;
  int nw0 = blockIdx.y * 256 + wv * 64;
  const bf8v* Ah = (const bf8v*)(ws + OFF_AHI);
  const bf8v* Al = (const bf8v*)(ws + OFF_ALO);
  const bf8v* Bh = (const bf8v*)(ws + OFF_BHI);
  const bf8v* Bl = (const bf8v*)(ws + OFF_BLO);
  int mt0 = blockIdx.x * 4;
  int nt0 = nw0 >> 4;

  f4v acc[4][4];
#pragma unroll
  for (int mi = 0; mi < 4; ++mi)
#pragma unroll
    for (int ni = 0; ni < 4; ++ni) acc[mi][ni] = (f4v){0.f, 0.f, 0.f, 0.f};

  for (int kc = 0; kc < 8; ++kc) {
    bf8v ah[4], al[4];
#pragma unroll
    for (int mi = 0; mi < 4; ++mi) {
      int idx = (((mt0 + mi) << 3) + kc) * 64 + lane;
      ah[mi] = Ah[idx];
      al[mi] = Al[idx];
    }
#pragma unroll
    for (int ni = 0; ni < 4; ++ni) {
      int idx = (((nt0 + ni) << 3) + kc) * 64 + lane;
      bf8v bh = Bh[idx];
      bf8v bl = Bl[idx];
#pragma unroll
      for (int mi = 0; mi < 4; ++mi) {
        acc[mi][ni] = __builtin_amdgcn_mfma_f32_16x16x32_bf16(ah[mi], bh, acc[mi][ni], 0, 0, 0);
        acc[mi][ni] = __builtin_amdgcn_mfma_f32_16x16x32_bf16(al[mi], bh, acc[mi][ni], 0, 0, 0);
        acc[mi][ni] = __builtin_amdgcn_mfma_f32_16x16x32_bf16(ah[mi], bl, acc[mi][ni], 0, 0, 0);
      }
    }
  }

  float bpv[4];
#pragma unroll
  for (int ni = 0; ni < 4; ++ni) bpv[ni] = bp[nw0 + ni * 16 + ln];
  float* logp = out + OUT_LOGP;
  float* pmax = ws + OFF_PMAX;
  float* psum = ws + OFF_PSUM;
  int* pai = (int*)(ws + OFF_PAI);
  int ntidx = blockIdx.y * 4 + wv;

#pragma unroll
  for (int mi = 0; mi < 4; ++mi) {
    int row_base = m0 + mi * 16 + quad * 4;
#pragma unroll
    for (int r = 0; r < 4; ++r) {
      int row = row_base + r;
      if (row < 1504) {
        float x0 = acc[mi][0][r] + bpv[0];
        float x1 = acc[mi][1][r] + bpv[1];
        float x2 = acc[mi][2][r] + bpv[2];
        float x3 = acc[mi][3][r] + bpv[3];
        long long ro = (long long)row * VV + nw0 + ln;
        logp[ro]      = x0;
        logp[ro + 16] = x1;
        logp[ro + 32] = x2;
        logp[ro + 48] = x3;
        // row max over this wave's 64 cols
        float mx = fmaxf(fmaxf(x0, x1), fmaxf(x2, x3));
#pragma unroll
        for (int msk = 1; msk < 16; msk <<= 1) mx = fmaxf(mx, __shfl_xor(mx, msk, 64));
        float it = 1.0f / temp[row / 47];
        float s = expf((x0 - mx) * it) + expf((x1 - mx) * it)
                + expf((x2 - mx) * it) + expf((x3 - mx) * it);
        // argmax (np first-occurrence tie-break: strict >, then smaller col)
        float bv = x0; int bc = nw0 + ln;
        if (x1 > bv) { bv = x1; bc = nw0 + 16 + ln; }
        if (x2 > bv) { bv = x2; bc = nw0 + 32 + ln; }
        if (x3 > bv) { bv = x3; bc = nw0 + 48 + ln; }
#pragma unroll
        for (int msk = 1; msk < 16; msk <<= 1) {
          s += __shfl_xor(s, msk, 64);
          float ov = __shfl_xor(bv, msk, 64);
          int oc = __shfl_xor(bc, msk, 64);
          if (ov > bv || (ov == bv && oc < bc)) { bv = ov; bc = oc; }
        }
        if (ln == 0) {
          long long ii = (long long)row * 500 + ntidx;
          pmax[ii] = mx;
          psum[ii] = s;
          pai[ii] = bc;
        }
      }
    }
  }
}

// ---------------- k_E0: reduce per-tile partials -> row stats + txt ----------------
__global__ __launch_bounds__(256) void k_E0(const int* __restrict__ length,
    const float* __restrict__ temp, float* __restrict__ ws, float* __restrict__ out)
{
  int i = blockIdx.x, tid = threadIdx.x;
  int b = i / ST, t = i % ST;
  float* txt = out + OUT_TXT;
  if (t >= length[b] - 1) { if (tid == 0) txt[i] = 0.f; return; }
  const float* pmax = ws + OFF_PMAX + (long long)i * 500;
  const float* psum = ws + OFF_PSUM + (long long)i * 500;
  const int* pai = (int*)(ws + OFF_PAI) + (long long)i * 500;
  __shared__ float sred[4]; __shared__ float s2[4]; __shared__ float s3[4]; __shared__ int s4[4];
  int w = tid >> 6;
  float mx = -3.4e38f;
  for (int nt = tid; nt < 500; nt += 256) mx = fmaxf(mx, pmax[nt]);
  for (int o = 32; o; o >>= 1) mx = fmaxf(mx, __shfl_xor(mx, o, 64));
  if ((tid & 63) == 0) sred[w] = mx;
  __syncthreads();
  float M = fmaxf(fmaxf(sred[0], sred[1]), fmaxf(sred[2], sred[3]));
  float it = 1.0f / temp[b];
  float S = 0.f; float bv = -3.4e38f; int bi = 0;
  for (int nt = tid; nt < 500; nt += 256) {
    float pm = pmax[nt];
    S += psum[nt] * expf((pm - M) * it);
    int ii = pai[nt];
    if (pm > bv || (pm == bv && ii < bi)) { bv = pm; bi = ii; }
  }
  for (int o = 32; o; o >>= 1) {
    S += __shfl_xor(S, o, 64);
    float vv = __shfl_xor(bv, o, 64);
    int ii = __shfl_xor(bi, o, 64);
    if (vv > bv || (vv == bv && ii < bi)) { bv = vv; bi = ii; }
  }
  if ((tid & 63) == 0) { s2[w] = S; s3[w] = bv; s4[w] = bi; }
  __syncthreads();
  if (tid == 0) {
    float St = s2[0] + s2[1] + s2[2] + s2[3];
    float bvv = s3[0]; int bii = s4[0];
    for (int u = 1; u < 4; ++u)
      if (s3[u] > bvv || (s3[u] == bvv && s4[u] < bii)) { bvv = s3[u]; bii = s4[u]; }
    ws[OFF_ROWM + i] = M;
    ws[OFF_ROWLS + i] = logf(St);
    txt[i] = (float)bii;
  }
}

// ---------------- k_E: in-place logits -> logp ----------------
__global__ __launch_bounds__(256) void k_E(const int* __restrict__ length,
    const float* __restrict__ temp, const float* __restrict__ ws, float* __restrict__ out)
{
  int i = blockIdx.y;
  int f4 = blockIdx.x * 256 + threadIdx.x;
  if (f4 >= 8000) return;
  int b = i / ST, t = i % ST;
  float4* p = (float4*)(out + OUT_LOGP + (long long)i * VV) + f4;
  if (t >= length[b] - 1) { *p = make_float4(0.f, 0.f, 0.f, 0.f); return; }
  float M = ws[OFF_ROWM + i], LS = ws[OFF_ROWLS + i];
  float it = 1.0f / temp[b];
  float4 x = *p;
  x.x = (x.x - M) * it - LS;
  x.y = (x.y - M) * it - LS;
  x.z = (x.z - M) * it - LS;
  x.w = (x.w - M) * it - LS;
  *p = x;
}

// ---------------- launch ----------------
extern "C" void kernel_launch(void* const* d_in, const int* in_sizes, int n_in,
                              void* d_out, int out_size, void* d_ws, size_t ws_size,
                              hipStream_t stream) {
  const float* image = (const float*)d_in[0];
  const float* vp    = (const float*)d_in[1];
  const float* label = (const float*)d_in[2];
  const float* topic = (const float*)d_in[3];
  const float* temp  = (const float*)d_in[4];
  const int*   text  = (const int*)d_in[5];
  const int*   length= (const int*)d_in[6];
  const float* emb   = (const float*)d_in[7];
  const float* Wv  = (const float*)d_in[8];  const float* bv  = (const float*)d_in[9];
  const float* Wh  = (const float*)d_in[10]; const float* bh  = (const float*)d_in[11];
  const float* Wm  = (const float*)d_in[12]; const float* bm  = (const float*)d_in[13];
  const float* Wih = (const float*)d_in[14]; const float* bih = (const float*)d_in[15];
  const float* Whh = (const float*)d_in[16]; const float* bhh = (const float*)d_in[17];
  const float* Wfc = (const float*)d_in[18]; const float* bfc = (const float*)d_in[19];
  const float* Whh2= (const float*)d_in[20]; const float* bhh2= (const float*)d_in[21];
  const float* Wsw = (const float*)d_in[22]; const float* bsw = (const float*)d_in[23];
  const float* Wz  = (const float*)d_in[24]; const float* bz  = (const float*)d_in[25];
  const float* Wp  = (const float*)d_in[26]; const float* bp  = (const float*)d_in[27];
  float* ws = (float*)d_ws;
  float* out = (float*)d_out;

  hipMemsetAsync(ws + OFF_CNT, 0, 64, stream);
  k_prep<<<32, 256, 0, stream>>>(image, vp, label, topic, Wh, bh, Wm, bm, Wih, bih, bhh, ws);
  k_v<<<dim3(4, 32), 256, 0, stream>>>(image, Wv, bv, ws);
  k_gpre<<<dim3(16, 32), 256, 0, stream>>>(emb, text, Wih, ws);
  k_recur<<<64, 128, 0, stream>>>(Whh, ws);
  k_fc<<<dim3(8, 32), 256, 0, stream>>>(Wfc, bfc, ws);
  k_hs<<<dim3(8, 32), 256, 0, stream>>>(Whh2, bhh2, Wsw, bsw, ws);
  k_att<<<dim3(47, 32), 256, 0, stream>>>(image, Wz, bz, length, ws, out);
  k_cvtA<<<192, 256, 0, stream>>>(ws);
  k_cvtB<<<4000, 256, 0, stream>>>(Wp, ws);
  k_Dm<<<dim3(24, 125), 256, 0, stream>>>(bp, temp, ws, out);
  k_E0<<<1504, 256, 0, stream>>>(length, temp, ws, out);
  k_E<<<dim3(32, 1504), 256, 0, stream>>>(length, temp, ws, out);
}